// Round 3
// baseline (540.175 us; speedup 1.0000x reference)
//
#include <hip/hip_runtime.h>

#define N_NODES 100000
#define D_FEAT 128
#define N_CLASSES 32
#define BSHIFT 7
#define BNODES 128                     // nodes per bucket = 1<<BSHIFT
#define NB 782                         // ceil(N_NODES/BNODES)
#define EPB 4096                       // edges per block in hist/bucket passes

// ---------- projection: y = x @ W^T, 8 nodes per thread ----------
__global__ __launch_bounds__(256) void gin_project8(
    const float* __restrict__ x, const float* __restrict__ W,
    float* __restrict__ y, int n_octs) {
  __shared__ float Wt[D_FEAT * N_CLASSES];  // Wt[d*32+c] = W[c*128+d]
  int tid = threadIdx.x;
  for (int i = tid; i < D_FEAT * N_CLASSES; i += 256) {
    int c = i >> 7, d = i & 127;
    Wt[d * N_CLASSES + c] = W[i];
  }
  __syncthreads();
  int gid = blockIdx.x * 256 + tid;
  int q = gid >> 5, c = gid & 31;
  if (q >= n_octs) return;
  int n0 = q * 8;
  const float4* x4 = (const float4*)x;
  float a[8] = {0.f, 0.f, 0.f, 0.f, 0.f, 0.f, 0.f, 0.f};
  for (int d4 = 0; d4 < D_FEAT / 4; ++d4) {
    float4 xv[8];
#pragma unroll
    for (int k = 0; k < 8; ++k) xv[k] = x4[(size_t)(n0 + k) * 32 + d4];
    int base = d4 * 4 * N_CLASSES + c;
    float w0 = Wt[base], w1 = Wt[base + 32], w2 = Wt[base + 64], w3 = Wt[base + 96];
#pragma unroll
    for (int k = 0; k < 8; ++k)
      a[k] += xv[k].x * w0 + xv[k].y * w1 + xv[k].z * w2 + xv[k].w * w3;
  }
#pragma unroll
  for (int k = 0; k < 8; ++k) y[(size_t)(n0 + k) * 32 + c] = a[k];
}

// ---------- pass A: bucket histogram (LDS-aggregated) ----------
__global__ __launch_bounds__(256) void gin_hist(
    const int* __restrict__ dst, int* __restrict__ gbhist, int E) {
  __shared__ int h[NB];
  int tid = threadIdx.x;
  for (int i = tid; i < NB; i += 256) h[i] = 0;
  __syncthreads();
  int base = blockIdx.x * EPB;
#pragma unroll
  for (int j = 0; j < 16; ++j) {
    int e = base + j * 256 + tid;
    if (e < E) atomicAdd(&h[dst[e] >> BSHIFT], 1);
  }
  __syncthreads();
  for (int i = tid; i < NB; i += 256) {
    int v = h[i];
    if (v) atomicAdd(&gbhist[i], v);
  }
}

// ---------- pass B: exclusive scan of 782 bucket counts (one block) ----------
__global__ __launch_bounds__(1024) void gin_scan(
    const int* __restrict__ gbhist, int* __restrict__ boff,
    int* __restrict__ gcursor) {
  __shared__ int s[1024];
  int tid = threadIdx.x;
  int v = (tid < NB) ? gbhist[tid] : 0;
  s[tid] = v;
  __syncthreads();
  for (int o = 1; o < 1024; o <<= 1) {
    int t = (tid >= o) ? s[tid - o] : 0;
    __syncthreads();
    s[tid] += t;
    __syncthreads();
  }
  if (tid < NB) {
    int excl = s[tid] - v;
    boff[tid] = excl;
    gcursor[tid] = excl;
  }
  if (tid == NB - 1) boff[NB] = s[tid];
}

// ---------- pass C: scatter edges into buckets, packed 4B ----------
// pack: src (17 bits) | dst_local (7 bits) << 17
__global__ __launch_bounds__(256) void gin_bucket(
    const int* __restrict__ src, const int* __restrict__ dst,
    int* __restrict__ gcursor, unsigned* __restrict__ bucketed, int E) {
  __shared__ int h[NB];
  __shared__ int rbase[NB];
  int tid = threadIdx.x;
  for (int i = tid; i < NB; i += 256) h[i] = 0;
  __syncthreads();
  int ebase = blockIdx.x * EPB;
  int myd[16], myr[16];
#pragma unroll
  for (int j = 0; j < 16; ++j) {
    int e = ebase + j * 256 + tid;
    if (e < E) {
      int d = dst[e];
      myd[j] = d;
      myr[j] = atomicAdd(&h[d >> BSHIFT], 1);
    } else {
      myd[j] = -1;
      myr[j] = 0;
    }
  }
  __syncthreads();
  for (int i = tid; i < NB; i += 256) {
    int v = h[i];
    rbase[i] = v ? atomicAdd(&gcursor[i], v) : 0;  // contiguous run per (block,bucket)
  }
  __syncthreads();
#pragma unroll
  for (int j = 0; j < 16; ++j) {
    if (myd[j] >= 0) {
      int e = ebase + j * 256 + tid;
      int d = myd[j];
      int pos = rbase[d >> BSHIFT] + myr[j];
      bucketed[pos] = (unsigned)src[e] | ((unsigned)(d & (BNODES - 1)) << 17);
    }
  }
}

// ---------- pass D: per-bucket aggregation in LDS, dense write ----------
__global__ __launch_bounds__(256) void gin_aggregate(
    const int* __restrict__ boff, const unsigned* __restrict__ bucketed,
    const float* __restrict__ y, const float* __restrict__ b,
    float* __restrict__ out) {
  __shared__ float acc[BNODES * N_CLASSES];  // 16 KB
  int tid = threadIdx.x;
  for (int i = tid; i < BNODES * N_CLASSES; i += 256) acc[i] = 0.f;
  int bk = blockIdx.x;
  int start = boff[bk], end = boff[bk + 1];
  int g = tid >> 5, c = tid & 31;
  float bc = b[c];
  __syncthreads();
  // 8 groups/block, each group 4 independent edges per iteration (MLP)
  for (int i = start + g * 4; i < end; i += 32) {
    int n = end - i;
    unsigned p[4];
    float v[4];
#pragma unroll
    for (int j = 0; j < 4; ++j)
      if (j < n) p[j] = bucketed[i + j];
#pragma unroll
    for (int j = 0; j < 4; ++j)
      if (j < n) v[j] = y[(size_t)(p[j] & 0x1FFFF) * N_CLASSES + c];
#pragma unroll
    for (int j = 0; j < 4; ++j)
      if (j < n) atomicAdd(&acc[(p[j] >> 17) * N_CLASSES + c], v[j]);
  }
  __syncthreads();
  size_t gbase = (size_t)bk * (BNODES * N_CLASSES);
  for (int i = tid; i < BNODES * N_CLASSES; i += 256) {
    size_t gi = gbase + i;
    if (gi < (size_t)N_NODES * N_CLASSES) out[gi] = acc[i] + y[gi] + bc;
  }
}

// ---------- fallback: atomic scatter (round-1 style) ----------
__global__ __launch_bounds__(256) void gin_bias_init(
    const float* __restrict__ y, const float* __restrict__ b,
    float* __restrict__ out) {
  int gid = blockIdx.x * 256 + threadIdx.x;
  if (gid < N_NODES * N_CLASSES) out[gid] = y[gid] + b[gid & 31];
}
__global__ __launch_bounds__(256) void gin_scatter_fb(
    const int* __restrict__ src, const int* __restrict__ dst,
    const float* __restrict__ y, float* __restrict__ out, int n_edges) {
  long long gid = (long long)blockIdx.x * 256 + threadIdx.x;
  int e = (int)(gid >> 5);
  int c = (int)(gid & 31);
  if (e >= n_edges) return;
  int s = src[e];
  int d = dst[e];
  atomicAdd(&out[(size_t)d * N_CLASSES + c], y[(size_t)s * N_CLASSES + c]);
}

extern "C" void kernel_launch(void* const* d_in, const int* in_sizes, int n_in,
                              void* d_out, int out_size, void* d_ws, size_t ws_size,
                              hipStream_t stream) {
  const float* x = (const float*)d_in[0];
  const int* edge_index = (const int*)d_in[1];
  const float* W = (const float*)d_in[2];
  const float* b = (const float*)d_in[3];
  float* out = (float*)d_out;

  int E = in_sizes[1] / 2;
  const int* src = edge_index;
  const int* dst = edge_index + E;

  // workspace layout
  char* ws = (char*)d_ws;
  size_t sz_y = (size_t)N_NODES * N_CLASSES * 4;            // 12.8 MB
  size_t sz_bucketed = (((size_t)E * 4) + 15) & ~15ull;     // 6.4 MB
  size_t sz_cnt = ((size_t)(NB + 1) * 4 + 15) & ~15ull;

  float* y = (float*)ws;
  unsigned* bucketed = (unsigned*)(ws + sz_y);
  int* gbhist = (int*)(ws + sz_y + sz_bucketed);
  int* boff = (int*)(ws + sz_y + sz_bucketed + sz_cnt);
  int* gcursor = (int*)(ws + sz_y + sz_bucketed + 2 * sz_cnt);
  size_t need = sz_y + sz_bucketed + 3 * sz_cnt;

  // projection (shared by both paths)
  int n_octs = N_NODES / 8;  // 12500 exact
  gin_project8<<<(n_octs * 32 + 255) / 256, 256, 0, stream>>>(x, W, y, n_octs);

  if (ws_size < need) {
    gin_bias_init<<<(N_NODES * N_CLASSES + 255) / 256, 256, 0, stream>>>(y, b, out);
    long long t2 = (long long)E * N_CLASSES;
    gin_scatter_fb<<<(int)((t2 + 255) / 256), 256, 0, stream>>>(src, dst, y, out, E);
    return;
  }

  int gEdges = (E + EPB - 1) / EPB;  // 391
  hipMemsetAsync(gbhist, 0, (size_t)NB * 4, stream);
  gin_hist<<<gEdges, 256, 0, stream>>>(dst, gbhist, E);
  gin_scan<<<1, 1024, 0, stream>>>(gbhist, boff, gcursor);
  gin_bucket<<<gEdges, 256, 0, stream>>>(src, dst, gcursor, bucketed, E);
  gin_aggregate<<<NB, 256, 0, stream>>>(boff, bucketed, y, b, out);
}